// Round 9
// baseline (33.335 us; speedup 1.0000x reference)
//
#include <hip/hip_runtime.h>
#include <hip/hip_bf16.h>

#define BB 4
#define NN 256
#define KK 32
#define DD 32
#define HH 8
#define NROWS 1024            // proj rows: e = 1..1024 stored at e-1
#define NPTS (BB * NN * NN)   // 262144
#define NNSQ (NN * NN)        // 65536
#define TPB 1024              // threads (= points) per block
#define NBLK (NPTS / TPB)     // 256 blocks = 1 per CU
#define SLICE_US (NROWS * HH) // 8192 ushorts = 16KB per k-slice
#define SLOT_US  (2 * SLICE_US) // one phase-pair = 32KB

typedef __attribute__((ext_vector_type(8))) unsigned short ushort8;
typedef __attribute__((ext_vector_type(4))) int iv4;
typedef __attribute__((ext_vector_type(2))) int iv2;

#define FENCE  asm volatile("" ::: "memory")
#define LGKM0  asm volatile("s_waitcnt lgkmcnt(0)" ::: "memory")
#define BAR    __builtin_amdgcn_s_barrier()
#define VMW(n) asm volatile("s_waitcnt vmcnt(" #n ")" ::: "memory")

__device__ __forceinline__ unsigned short f2bf(float f) {
    unsigned u = __float_as_uint(f);
    unsigned r = (u + 0x7FFFu + ((u >> 16) & 1u)) >> 16;
    return (unsigned short)r;
}

__device__ __forceinline__ void gload16(const void* g, void* l) {
    __builtin_amdgcn_global_load_lds(
        (const __attribute__((address_space(1))) void*)g,
        (__attribute__((address_space(3))) void*)l,
        16, 0, 0);
}

// ---------------------------------------------------------------------------
// Kernel A: proj[k][e-1][h] = sum_d feat[e][d] * W[k][d][h]   (bf16, e=1..1024)
// ---------------------------------------------------------------------------
__global__ __launch_bounds__(256) void build_proj_bf16(
    const float* __restrict__ feat,    // [1025][32]
    const float* __restrict__ w,       // [32][256] (d*8+h)
    unsigned short* __restrict__ proj) // [32][1024][8]
{
    int t  = blockIdx.x * 256 + threadIdx.x;  // 0..32767
    int k  = t >> 10;                         // uniform per block
    int e  = (t & 1023) + 1;

    const float* frow = feat + (size_t)e * DD;
    const float* wrow = w + (size_t)k * DD * HH;

    float acc[HH];
#pragma unroll
    for (int h = 0; h < HH; ++h) acc[h] = 0.0f;

#pragma unroll
    for (int d = 0; d < DD; ++d) {
        float f = frow[d];
#pragma unroll
        for (int h = 0; h < HH; ++h) acc[h] = fmaf(f, wrow[d * HH + h], acc[h]);
    }

    ushort8 o;
#pragma unroll
    for (int h = 0; h < HH; ++h) o[h] = f2bf(acc[h]);
    *(ushort8*)(proj + (size_t)t * HH) = o;
}

// ---------------------------------------------------------------------------
// Kernel B v9: uniform-trio pipeline. Per phase: issue {1 idx load (own row),
// 2 global_load_lds} with 3-phase lead into a 4-slot ring; one VMW(6)+BAR.
// idx loads stay continuously in flight (same FIFO cadence as stages).
// No LDS writes in the loop (no ibuf); 16 barriers total.
// E = ints per index element (2 = int64 input, 1 = int32).
// ---------------------------------------------------------------------------
template <int E>
__global__ __launch_bounds__(TPB) void attn_bias_v9(
    const int* __restrict__ sp,               // [NPTS] (*E)
    const int* __restrict__ ei,               // [NPTS*KK] (*E)
    const float* __restrict__ semb,           // [512][8]
    const unsigned short* __restrict__ proj,  // [32][1024][8] bf16
    float* __restrict__ out)                  // [BB][HH][NNSQ]
{
    __shared__ __align__(16) unsigned short tbuf[4 * SLOT_US]; // 128KB ring
    __shared__ __align__(16) unsigned short zrow[8];           // zero row (e==0)

    const int tid = threadIdx.x;
    const int pg  = blockIdx.x * TPB + tid;

    const char* myrow = (const char*)ei + (size_t)pg * (KK * 4 * E); // own idx row

    iv4 ix4[4];   // rotating idx regs (E==2); all indices fold to literals
    iv2 ix2[4];   // rotating idx regs (E==1)

    float acc[HH];
#pragma unroll
    for (int h = 0; h < HH; ++h) acc[h] = 0.0f;
    int cnt = 0;

#define ISSUE_I(q) do {                                                        \
        if (E == 2) ix4[(q) & 3] = *(const iv4*)(myrow + (q) * 16);            \
        else        ix2[(q) & 3] = *(const iv2*)(myrow + (q) * 8);             \
    } while (0)

#define STAGE2(q) do {                                                         \
        gload16(proj + (size_t)(2 * (q)) * SLICE_US + tid * HH,                \
                &tbuf[((q) & 3) * SLOT_US + tid * HH]);                        \
        gload16(proj + (size_t)(2 * (q) + 1) * SLICE_US + tid * HH,            \
                &tbuf[((q) & 3) * SLOT_US + SLICE_US + tid * HH]);             \
    } while (0)

#define COMPUTE(p) do {                                                        \
        int e0, e1;                                                            \
        if (E == 2) { e0 = ix4[(p) & 3].x; e1 = ix4[(p) & 3].z; }              \
        else        { e0 = ix2[(p) & 3].x; e1 = ix2[(p) & 3].y; }              \
        cnt += (e0 != 0) + (e1 != 0);                                          \
        const unsigned short* tb = &tbuf[((p) & 3) * SLOT_US];                 \
        const unsigned short* a0 = e0 ? tb + (e0 - 1) * HH : zrow;             \
        const unsigned short* a1 = e1 ? tb + SLICE_US + (e1 - 1) * HH : zrow;  \
        ushort8 w0 = *(const ushort8*)a0;                                      \
        ushort8 w1 = *(const ushort8*)a1;                                      \
        _Pragma("unroll")                                                      \
        for (int h = 0; h < HH; ++h) {                                         \
            acc[h] += __uint_as_float(((unsigned)w0[h]) << 16);                \
            acc[h] += __uint_as_float(((unsigned)w1[h]) << 16);                \
        }                                                                      \
    } while (0)

#define PHASE(p, WN) do {                                                      \
        if ((p) <= 12) { ISSUE_I((p) + 3); STAGE2((p) + 3); }                  \
        COMPUTE(p);                                                            \
        FENCE;                                                                 \
        if ((WN) == 6) VMW(6); else if ((WN) == 3) VMW(3); else VMW(0);        \
        BAR;                                                                   \
    } while (0)

    // ---------------- prologue: trios 0,1,2 ----------------
    ISSUE_I(0); STAGE2(0);
    ISSUE_I(1); STAGE2(1);
    ISSUE_I(2); STAGE2(2);
    if (tid == 0) *(float4*)zrow = make_float4(0.f, 0.f, 0.f, 0.f);
    FENCE;
    VMW(6);   // 9 outstanding -> 6: drains trio 0 (slot0 + ix[0])
    LGKM0;    // zrow visible
    BAR;

    // ---------------- 16 phases ----------------
    PHASE(0, 6);  PHASE(1, 6);  PHASE(2, 6);  PHASE(3, 6);
    PHASE(4, 6);  PHASE(5, 6);  PHASE(6, 6);  PHASE(7, 6);
    PHASE(8, 6);  PHASE(9, 6);  PHASE(10, 6); PHASE(11, 6);
    PHASE(12, 6); PHASE(13, 3); PHASE(14, 0);
    COMPUTE(15);  // slot 3 drained at ph14's VMW(0)+BAR

    // ---------------- epilogue: spatial bias + write ----------------
    int sv = (E == 2) ? (int)((const long long*)sp)[pg] : sp[pg];
    const float4* srow = (const float4*)(semb + (size_t)sv * HH);
    float4 s0v = srow[0], s1v = srow[1];
    float sb[HH] = {s0v.x, s0v.y, s0v.z, s0v.w, s1v.x, s1v.y, s1v.z, s1v.w};

    float inv = 1.0f / (float)(cnt ? cnt : 1);
    float* o = out + (size_t)(pg >> 16) * (HH * NNSQ) + (pg & (NNSQ - 1));
#pragma unroll
    for (int h = 0; h < HH; ++h)
        o[(size_t)h * NNSQ] = sb[h] + acc[h] * inv;

#undef ISSUE_I
#undef STAGE2
#undef COMPUTE
#undef PHASE
}

extern "C" void kernel_launch(void* const* d_in, const int* in_sizes, int n_in,
                              void* d_out, int out_size, void* d_ws, size_t ws_size,
                              hipStream_t stream) {
    const int*   sp = (const int*)d_in[0];    // spatial_pos  [4,256,256]
    const int*   ei = (const int*)d_in[1];    // edge_input   [4,256,256,32]
    const float* se = (const float*)d_in[2];  // spatial_emb  [512,8]
    const float* fe = (const float*)d_in[3];  // edge_feat_emb[1025,32]
    const float* pw = (const float*)d_in[4];  // edge_pos_emb [32,256]
    float* out = (float*)d_out;

    const bool i64 = (in_sizes[0] == 2 * NPTS);
    unsigned short* proj = (unsigned short*)d_ws;   // 32*1024*8*2 = 512KB

    build_proj_bf16<<<128, 256, 0, stream>>>(fe, pw, proj);

    if (i64) attn_bias_v9<2><<<NBLK, TPB, 0, stream>>>(sp, ei, se, proj, out);
    else     attn_bias_v9<1><<<NBLK, TPB, 0, stream>>>(sp, ei, se, proj, out);
}

// Round 11
// 30.501 us; speedup vs baseline: 1.0929x; 1.0929x over previous
//
#include <hip/hip_runtime.h>
#include <hip/hip_bf16.h>

#define BB 4
#define NN 256
#define KK 32
#define DD 32
#define HH 8
#define NROWS 1024            // proj rows: e = 1..1024 stored at e-1
#define NPTS (BB * NN * NN)   // 262144
#define NNSQ (NN * NN)        // 65536
#define TPB 512               // threads (= points) per block
#define NBLK (NPTS / TPB)     // 512 blocks = 2 per CU
#define SLICE_US (NROWS * HH) // 8192 ushorts = 16KB per k-slice

typedef __attribute__((ext_vector_type(8))) unsigned short ushort8;
typedef __attribute__((ext_vector_type(4))) int iv4;

#define FENCE  asm volatile("" ::: "memory")
#define LGKM0  asm volatile("s_waitcnt lgkmcnt(0)" ::: "memory")
#define BAR    __builtin_amdgcn_s_barrier()
#define VMW(n) asm volatile("s_waitcnt vmcnt(" #n ")" ::: "memory")

__device__ __forceinline__ unsigned short f2bf(float f) {
    unsigned u = __float_as_uint(f);
    unsigned r = (u + 0x7FFFu + ((u >> 16) & 1u)) >> 16;
    return (unsigned short)r;
}

__device__ __forceinline__ void gload16(const void* g, void* l) {
    __builtin_amdgcn_global_load_lds(
        (const __attribute__((address_space(1))) void*)g,
        (__attribute__((address_space(3))) void*)l,
        16, 0, 0);
}

// ---------------------------------------------------------------------------
// Kernel A: proj[k][e-1][h] = sum_d feat[e][d] * W[k][d][h]   (bf16, e=1..1024)
// ---------------------------------------------------------------------------
__global__ __launch_bounds__(256) void build_proj_bf16(
    const float* __restrict__ feat,    // [1025][32]
    const float* __restrict__ w,       // [32][256] (d*8+h)
    unsigned short* __restrict__ proj) // [32][1024][8]
{
    int t  = blockIdx.x * 256 + threadIdx.x;  // 0..32767
    int k  = t >> 10;                         // uniform per block
    int e  = (t & 1023) + 1;

    const float* frow = feat + (size_t)e * DD;
    const float* wrow = w + (size_t)k * DD * HH;

    float acc[HH];
#pragma unroll
    for (int h = 0; h < HH; ++h) acc[h] = 0.0f;

#pragma unroll
    for (int d = 0; d < DD; ++d) {
        float f = frow[d];
#pragma unroll
        for (int h = 0; h < HH; ++h) acc[h] = fmaf(f, wrow[d * HH + h], acc[h]);
    }

    ushort8 o;
#pragma unroll
    for (int h = 0; h < HH; ++h) o[h] = f2bf(acc[h]);
    *(ushort8*)(proj + (size_t)t * HH) = o;
}

// ---------------------------------------------------------------------------
// Kernel B v11: v10 with the block-base fix: iv4s per point = 8*E, so
// bi4 = blockIdx.x * TPB * (8*E). (v10 used 4*E -> every block >0 gathered
// with wrong indices.) Schedule unchanged: 512-thread blocks, 2/CU; 32
// phases x 1 slice; 3-slot gload_lds ring, 2-phase lead; idx pieces smeared
// one per phase behind the stages, hand-counted per-phase vmcnt.
// E = ints per index element (2=int64, 1=int32).
// ---------------------------------------------------------------------------
template <int E>
__global__ __launch_bounds__(TPB, 4) void attn_bias_v11(
    const int* __restrict__ sp,               // [NPTS] (*E)
    const int* __restrict__ ei,               // [NPTS*KK] (*E)
    const float* __restrict__ semb,           // [512][8]
    const unsigned short* __restrict__ proj,  // [32][1024][8] bf16
    float* __restrict__ out)                  // [BB][HH][NNSQ]
{
    __shared__ __align__(16) unsigned short tbuf[3 * SLICE_US];  // 48KB ring
    __shared__ __align__(16) unsigned short zrow[8];             // zero row
    __shared__ unsigned short ibuf[2][8][TPB + 2];               // 16.1KB

    const int tid = threadIdx.x;
    const int pg  = blockIdx.x * TPB + tid;

    const iv4* EI4 = (const iv4*)ei;
    const size_t bi4 = (size_t)blockIdx.x * TPB * (8 * E);  // iv4s/point = 8E (FIX)

    iv4 cv0, cv1, cv2, cv3;   // piece staging regs (named: no dynamic indexing)

    float acc[HH];
#pragma unroll
    for (int h = 0; h < HH; ++h) acc[h] = 0.0f;
    int cnt = 0;

// --- piece loads (coalesced 64B clusters) ---
#define PIECE2(g, i, cv) { int j=(i)*TPB+tid, pt=j>>2, q=j&3;                  \
        cv = EI4[bi4 + (size_t)pt*16 + 4*(g) + q]; }
#define PIECE1(g, i, cv) { int j=(i)*TPB+tid, pt=j>>1, q=j&1;                  \
        cv = EI4[bi4 + (size_t)pt*8 + 2*(g) + q]; }
#define P0(g) do{ if constexpr (E==2) PIECE2(g,0,cv0) else PIECE1(g,0,cv0) }while(0);
#define P1(g) do{ if constexpr (E==2) PIECE2(g,1,cv1) }while(0);
#define P2(g) do{ if constexpr (E==2) PIECE2(g,2,cv2) else PIECE1(g,1,cv1) }while(0);
#define P3(g) do{ if constexpr (E==2) PIECE2(g,3,cv3) }while(0);
#define PN

// --- ibuf scatter at window boundaries ---
#define WR2(nb, i, cv) { int j=(i)*TPB+tid, pt=j>>2, q=j&3;                    \
        ibuf[nb][2*q  ][pt] = (unsigned short)cv.x;                            \
        ibuf[nb][2*q+1][pt] = (unsigned short)cv.z; }
#define WR1(nb, i, cv) { int j=(i)*TPB+tid, pt=j>>1, q=j&1;                    \
        ibuf[nb][4*q  ][pt] = (unsigned short)cv.x;                            \
        ibuf[nb][4*q+1][pt] = (unsigned short)cv.y;                            \
        ibuf[nb][4*q+2][pt] = (unsigned short)cv.z;                            \
        ibuf[nb][4*q+3][pt] = (unsigned short)cv.w; }
#define WCY(nb) do{ if constexpr (E==2) { WR2(nb,0,cv0) WR2(nb,1,cv1)          \
        WR2(nb,2,cv2) WR2(nb,3,cv3) } else { WR1(nb,0,cv0) WR1(nb,1,cv1) } }while(0);
#define WCN

// --- stage slice q into slot q%3 (lane-16B linear dest, 2 gloads) ---
#define STG(q) do{                                                             \
        gload16(proj + (size_t)(q)*SLICE_US + (size_t)tid*8,                   \
                &tbuf[((q)%3)*SLICE_US + tid*8]);                              \
        gload16(proj + (size_t)(q)*SLICE_US + (size_t)(TPB+tid)*8,             \
                &tbuf[((q)%3)*SLICE_US + (TPB+tid)*8]);                        \
    }while(0);

// --- one hop gather + accumulate ---
#define HOP(p) do{                                                             \
        int e = ibuf[((p)>>3)&1][(p)&7][tid];                                  \
        cnt += (e != 0);                                                       \
        const unsigned short* a = e ? &tbuf[((p)%3)*SLICE_US + (e-1)*8] : zrow;\
        ushort8 w = *(const ushort8*)a;                                        \
        _Pragma("unroll")                                                      \
        for (int h = 0; h < HH; ++h)                                           \
            acc[h] += __uint_as_float(((unsigned)w[h]) << 16);                 \
    }while(0);

// --- one phase ---
#define PH(p, W2, W1, PSTMT, WCSTMT) do{                                       \
        if ((p) <= 29) STG((p)+2);                                             \
        PSTMT                                                                  \
        HOP(p);                                                                \
        WCSTMT                                                                 \
        FENCE;                                                                 \
        if constexpr (E==2) { VMW(W2); } else { VMW(W1); }                     \
        LGKM0;                                                                 \
        BAR;                                                                   \
    }while(0)

    // ---------------- prologue ----------------
    int sv;
    if constexpr (E == 2) sv = (int)((const long long*)sp)[pg];
    else                  sv = sp[pg];
    FENCE;
    // chunk 0: all pieces now (ample lead before ph0)
    P0(0) P1(0) P2(0) P3(0)
    STG(0); STG(1);
    if (tid == 0) *(float4*)zrow = make_float4(0.f, 0.f, 0.f, 0.f);
    WCY(0)                 // compiler vmcnt-waits on cv regs; stages stay queued
    FENCE;
    VMW(2);                // drain S0 (and idx); keep S1 in flight
    LGKM0;
    BAR;

    // ---------------- 32 phases ----------------
    PH( 0, 2, 2, PN,    WCN);
    PH( 1, 2, 2, PN,    WCN);
    PH( 2, 3, 3, P0(1), WCN);
    PH( 3, 4, 3, P1(1), WCN);
    PH( 4, 4, 3, P2(1), WCN);
    PH( 5, 4, 3, P3(1), WCN);
    PH( 6, 3, 2, PN,    WCN);
    PH( 7, 2, 2, PN,    WCY(1));
    PH( 8, 2, 2, PN,    WCN);
    PH( 9, 2, 2, PN,    WCN);
    PH(10, 3, 3, P0(2), WCN);
    PH(11, 4, 3, P1(2), WCN);
    PH(12, 4, 3, P2(2), WCN);
    PH(13, 4, 3, P3(2), WCN);
    PH(14, 3, 2, PN,    WCN);
    PH(15, 2, 2, PN,    WCY(0));
    PH(16, 2, 2, PN,    WCN);
    PH(17, 2, 2, PN,    WCN);
    PH(18, 3, 3, P0(3), WCN);
    PH(19, 4, 3, P1(3), WCN);
    PH(20, 4, 3, P2(3), WCN);
    PH(21, 4, 3, P3(3), WCN);
    PH(22, 3, 2, PN,    WCN);
    PH(23, 2, 2, PN,    WCY(1));
    PH(24, 2, 2, PN,    WCN);
    PH(25, 2, 2, PN,    WCN);
    PH(26, 2, 2, PN,    WCN);
    PH(27, 2, 2, PN,    WCN);
    PH(28, 2, 2, PN,    WCN);
    PH(29, 2, 2, PN,    WCN);
    PH(30, 0, 0, PN,    WCN);
    HOP(31);               // slot drained at ph30's vmcnt(0)+BAR

    // ---------------- epilogue: spatial bias + write ----------------
    const float4* srow = (const float4*)(semb + (size_t)sv * HH);
    float4 s0v = srow[0], s1v = srow[1];
    float sb[HH] = {s0v.x, s0v.y, s0v.z, s0v.w, s1v.x, s1v.y, s1v.z, s1v.w};

    float inv = 1.0f / (float)(cnt ? cnt : 1);
    float* o = out + (size_t)(pg >> 16) * (HH * NNSQ) + (pg & (NNSQ - 1));
#pragma unroll
    for (int h = 0; h < HH; ++h)
        o[(size_t)h * NNSQ] = sb[h] + acc[h] * inv;
}

extern "C" void kernel_launch(void* const* d_in, const int* in_sizes, int n_in,
                              void* d_out, int out_size, void* d_ws, size_t ws_size,
                              hipStream_t stream) {
    const int*   sp = (const int*)d_in[0];    // spatial_pos  [4,256,256]
    const int*   ei = (const int*)d_in[1];    // edge_input   [4,256,256,32]
    const float* se = (const float*)d_in[2];  // spatial_emb  [512,8]
    const float* fe = (const float*)d_in[3];  // edge_feat_emb[1025,32]
    const float* pw = (const float*)d_in[4];  // edge_pos_emb [32,256]
    float* out = (float*)d_out;

    const bool i64 = (in_sizes[0] == 2 * NPTS);
    unsigned short* proj = (unsigned short*)d_ws;   // 32*1024*8*2 = 512KB

    build_proj_bf16<<<128, 256, 0, stream>>>(fe, pw, proj);

    if (i64) attn_bias_v11<2><<<NBLK, TPB, 0, stream>>>(sp, ei, se, proj, out);
    else     attn_bias_v11<1><<<NBLK, TPB, 0, stream>>>(sp, ei, se, proj, out);
}